// Round 6
// baseline (56.267 us; speedup 1.0000x reference)
//
#include <hip/hip_runtime.h>
#include <hip/hip_bf16.h>
#include <math.h>

#define D_IN  128
#define NH    8
#define F_OUT 32
#define HID   256
#define D_EMB 64
#define BINS  200
#define FDIM  384
#define CAP   128

#define NSTAGE    32
#define VSRC_BASE 32   // 8 blocks
#define SKIP_BASE 40   // 8 blocks
#define ESC_BASE  48   // 4 blocks
#define SMS_BID   52   // 1 block
#define PRE1_BASE 53   // 16 blocks
#define SCAN_BASE 69   // 59 scan-only blocks
#define GRID      128
#define NSCAN     (NSTAGE + (GRID - SCAN_BASE))   // 91 scanning blocks

// ws ints: [0]=count [1]=flag_scan [2]=flag_proj [3]=flag_mlp
//          [16..) m_src[CAP] m_trg[CAP] m_bin[CAP]
// ws floats (base 512): vsrc[1024] strg[16] sms[8] escall[1600]
//                       skipb[512] pre1[256] out_ws[512] partial[32]

__device__ __forceinline__ float redw(float v) {
#pragma unroll
  for (int o = 32; o > 0; o >>= 1) v += __shfl_down(v, o, 64);
  return v;
}

__device__ __forceinline__ void block_release_add(int* flag) {
  __threadfence();                 // each thread releases its global writes
  __syncthreads();
  if (threadIdx.x == 0) atomicAdd(flag, 1);
}

__device__ __forceinline__ void block_wait(int* flag, int target) {
  if (threadIdx.x == 0) {
    while (__hip_atomic_load(flag, __ATOMIC_ACQUIRE, __HIP_MEMORY_SCOPE_AGENT) < target)
      __builtin_amdgcn_s_sleep(1);
  }
  __syncthreads();
  __threadfence();                 // acquire: subsequent reads see device state
}

__device__ __forceinline__ void do_scan(const int* __restrict__ etrg,
                                        const int* __restrict__ esrc,
                                        const int* __restrict__ ebin,
                                        int sid, int tid, int nE, int li, int ld,
                                        int* count, int* m_src, int* m_trg, int* m_bin) {
  const int gid = sid * 512 + tid;
  const int stride = NSCAN * 512;
  const int nE4 = nE >> 2;
  const int4* t4 = (const int4*)etrg;
  for (int e4 = gid; e4 < nE4; e4 += stride) {
    int4 t = t4[e4];
    int ev[4] = {t.x, t.y, t.z, t.w};
#pragma unroll
    for (int k = 0; k < 4; ++k) {
      if (ev[k] == li || ev[k] == ld) {
        int e = e4 * 4 + k;
        int pos = atomicAdd(count, 1);
        if (pos < CAP) { m_src[pos] = esrc[e]; m_trg[pos] = ev[k]; m_bin[pos] = ebin[e]; }
      }
    }
  }
  if (sid == NSTAGE && tid == 0) {   // tail (nE % 4)
    for (int e = nE4 * 4; e < nE; ++e) {
      int tv = etrg[e];
      if (tv == li || tv == ld) {
        int pos = atomicAdd(count, 1);
        if (pos < CAP) { m_src[pos] = esrc[e]; m_trg[pos] = tv; m_bin[pos] = ebin[e]; }
      }
    }
  }
}

__global__ __launch_bounds__(512, 1) void fused_k(
    const float* __restrict__ nf, const int* __restrict__ esrc,
    const int* __restrict__ etrg, const int* __restrict__ ebin,
    const float* __restrict__ ms, const int* __restrict__ li_p,
    const int* __restrict__ ld_p, const int* __restrict__ dist_p,
    const float* __restrict__ Wproj, const float* __restrict__ a_src,
    const float* __restrict__ a_trg, const float* __restrict__ Wms,
    const float* __restrict__ demb_g, const float* __restrict__ Wdist,
    const float* __restrict__ Wskip, const float* __restrict__ gbias,
    const float* __restrict__ demb_h, const float* __restrict__ W1,
    const float* __restrict__ b1, const float* __restrict__ W2,
    const float* __restrict__ b2, int nE,
    int* __restrict__ ws_i, float* __restrict__ fb, float* __restrict__ out) {
  int* count     = ws_i;
  int* flag_scan = ws_i + 1;
  int* flag_proj = ws_i + 2;
  int* flag_mlp  = ws_i + 3;
  int* m_src     = ws_i + 16;
  int* m_trg     = m_src + CAP;
  int* m_bin     = m_trg + CAP;
  float* vsrc    = fb;               // 1024
  float* strg    = fb + 1024;        // 16
  float* sms     = fb + 1040;        // 8
  float* escall  = fb + 1048;        // 1600
  float* skipb   = fb + 2648;        // 512
  float* pre1    = fb + 3160;        // 256
  float* out_ws  = fb + 3416;        // 512
  float* partial = fb + 3928;        // 32

  __shared__ int   s_es[CAP], s_tb[CAP], s_bn[CAP];
  __shared__ float s_p[CAP];
  __shared__ float s_den[2];
  __shared__ __align__(16) float s_vs[D_IN];
  __shared__ __align__(16) float s_agg[2][D_IN];
  __shared__ __align__(16) float s_out[512];
  __shared__ __align__(16) float s_emb[64];
  __shared__ float s_pr[8];
  __shared__ __align__(16) float s_nf2[2 * D_IN];
  __shared__ __align__(16) float s_vp[2][4][D_IN];

  const int bid = blockIdx.x, tid = threadIdx.x;
  const int wv = tid >> 6, ln = tid & 63;
  const int li = li_p[0], ld = ld_p[0];

  if (bid < NSTAGE) {
    // ===================== STAGE block =====================
    const int k = bid;
    const int R0 = k * 8;            // owns output rows [R0, R0+8)
    const int h = k >> 2;            // their head
    const int row = R0 + wv;         // this wave's row
    // register preload (scan-independent, issued at t=0)
    const float wpA = Wproj[row * D_IN + ln * 2];
    const float wpB = Wproj[row * D_IN + ln * 2 + 1];
    const float w1e = W1[(size_t)row * FDIM + HID + ln];
    const float w2v = W2[row];

    do_scan(etrg, esrc, ebin, k, tid, nE, li, ld, count, m_src, m_trg, m_bin);
    block_release_add(flag_scan);
    block_wait(flag_scan, GRID);

    // ---- proj phase: scores -> attn -> agg(head h) -> own 8 rows ----
    int cnt = *count; if (cnt > CAP) cnt = CAP;
    if (tid < cnt) {
      s_es[tid] = m_src[tid];
      s_tb[tid] = (m_trg[tid] == li) ? 0 : 1;
      s_bn[tid] = m_bin[tid];
    }
    if (tid < D_IN) s_vs[tid] = vsrc[h * D_IN + tid];
    __syncthreads();
    const float sms_h = sms[h], strg0 = strg[h], strg1 = strg[NH + h];
    for (int e = wv; e < cnt; e += 8) {       // wave per edge
      const float* nfr = nf + (size_t)s_es[e] * D_IN + ln * 2;
      float part = nfr[0] * s_vs[ln * 2] + nfr[1] * s_vs[ln * 2 + 1];
      part = redw(part);
      if (ln == 0) {
        float sc = part + (s_tb[e] ? strg1 : strg0) + sms_h + escall[s_bn[e] * NH + h];
        sc = sc > 0.f ? sc : 0.2f * sc;       // leaky_relu(0.2); global max cancels
        s_p[e] = expf(sc);
      }
    }
    __syncthreads();
    if (tid < 2) {
      float d = 1e-16f;
      for (int e = 0; e < cnt; ++e) if (s_tb[e] == (int)tid) d += s_p[e];
      s_den[tid] = d;
    }
    __syncthreads();
    if (tid < cnt) s_p[tid] = s_p[tid] / s_den[s_tb[tid]];
    __syncthreads();
    if (tid < 256) {                          // agg[t,d] for head h
      const int t = tid >> 7, d = tid & 127;
      float a = 0.f;
      for (int e = 0; e < cnt; ++e)
        if (s_tb[e] == t) a = fmaf(s_p[e], nf[(size_t)s_es[e] * D_IN + d], a);
      s_agg[t][d] = a;
    }
    __syncthreads();
    {
      float o0 = wpA * s_agg[0][ln * 2] + wpB * s_agg[0][ln * 2 + 1];
      float o1 = wpA * s_agg[1][ln * 2] + wpB * s_agg[1][ln * 2 + 1];
      o0 = redw(o0); o1 = redw(o1);
      if (ln == 0) {
        out_ws[row]       = o0 + skipb[row];
        out_ws[256 + row] = o1 + skipb[256 + row];
      }
    }
    block_release_add(flag_proj);
    block_wait(flag_proj, NSTAGE);

    // ---- MLP phase: emb (redundant, cheap) + own 8 rows from registers ----
    s_out[tid] = out_ws[tid];
    __syncthreads();
    if (tid < 64) {
      const int t = tid >> 5, f = tid & 31;
      float s = 0.f;
#pragma unroll
      for (int hh = 0; hh < NH; ++hh) s += s_out[t * 256 + hh * F_OUT + f];
      s = s * 0.125f + gbias[f];
      s_emb[tid] = s > 0.f ? s : expm1f(s);   // ELU
    }
    __syncthreads();
    {
      float acc = redw(w1e * s_emb[ln]);
      if (ln == 0) {
        float h1 = fmaxf(pre1[row] + acc, 0.f);
        s_pr[wv] = w2v * h1;
      }
    }
    __syncthreads();
    if (tid == 0) {
      float bp = 0.f;
#pragma unroll
      for (int w = 0; w < 8; ++w) bp += s_pr[w];
      partial[k] = bp;
      __threadfence();
      int ret = atomicAdd(flag_mlp, 1);
      if (ret == NSTAGE - 1) {               // last MLP block finalizes
        __threadfence();
        float s = b2[0];
        for (int j = 0; j < NSTAGE; ++j) s += partial[j];
        out[0] = s;
      }
    }
    return;
  }

  if (bid < SKIP_BASE) {
    // ===== vsrc/vtrg + strg for head h =====
    const int h = bid - VSRC_BASE;
    const int d = tid & 127, fg = tid >> 7;   // 4 groups x 8 f
    float as = 0.f, at = 0.f;
    for (int f = fg * 8; f < fg * 8 + 8; ++f) {
      float w = Wproj[(h * F_OUT + f) * D_IN + d];
      as = fmaf(a_src[h * F_OUT + f], w, as);
      at = fmaf(a_trg[h * F_OUT + f], w, at);
    }
    s_vp[0][fg][d] = as; s_vp[1][fg][d] = at;
    __syncthreads();
    if (tid < 128)
      vsrc[h * D_IN + tid] = s_vp[0][0][tid] + s_vp[0][1][tid] + s_vp[0][2][tid] + s_vp[0][3][tid];
    if (tid >= 128 && tid < 256) {
      int dd = tid - 128;
      s_vp[1][0][dd] = s_vp[1][0][dd] + s_vp[1][1][dd] + s_vp[1][2][dd] + s_vp[1][3][dd];
    }
    if (tid >= 256 && tid < 320) {
      int j = tid - 256;
      ((float4*)s_nf2)[j] = ((const float4*)(nf + (size_t)(j < 32 ? li : ld) * D_IN))[j & 31];
    }
    __syncthreads();
    if (wv < 2) {                             // strg[t,h] = nf2[t] . vtrg[h]
      float part = s_nf2[wv * D_IN + ln * 2] * s_vp[1][0][ln * 2]
                 + s_nf2[wv * D_IN + ln * 2 + 1] * s_vp[1][0][ln * 2 + 1];
      part = redw(part);
      if (ln == 0) strg[wv * NH + h] = part;
    }
  } else if (bid < ESC_BASE) {
    // ===== skipb rows [32p, 32p+32) =====
    const int base = (bid - SKIP_BASE) * 32;
    if (tid < 64)
      ((float4*)s_nf2)[tid] = ((const float4*)(nf + (size_t)(tid < 32 ? li : ld) * D_IN))[tid & 31];
    __syncthreads();
    for (int rd = 0; rd < 4; ++rd) {
      int r = base + rd * 8 + wv;
      float w0 = Wskip[r * D_IN + ln * 2], w1 = Wskip[r * D_IN + ln * 2 + 1];
      float o0 = w0 * s_nf2[ln * 2] + w1 * s_nf2[ln * 2 + 1];
      float o1 = w0 * s_nf2[D_IN + ln * 2] + w1 * s_nf2[D_IN + ln * 2 + 1];
      o0 = redw(o0); o1 = redw(o1);
      if (ln == 0) { skipb[r] = o0; skipb[256 + r] = o1; }
    }
  } else if (bid < SMS_BID) {
    // ===== escall bins [50p, 50p+50) =====
    const int p = bid - ESC_BASE;
    const int g = tid >> 3, l8 = tid & 7;
    for (int it = g; it < 50 * NH; it += 64) {
      int bin = p * 50 + (it >> 3), hh = it & 7;
      const float* de = demb_g + bin * D_EMB + l8 * 8;
      const float* wd = Wdist + hh * D_EMB + l8 * 8;
      float a = 0.f;
#pragma unroll
      for (int j = 0; j < 8; ++j) a = fmaf(de[j], wd[j], a);
#pragma unroll
      for (int o = 4; o > 0; o >>= 1) a += __shfl_down(a, o, 8);
      if (l8 == 0) escall[bin * NH + hh] = a;
    }
  } else if (bid < PRE1_BASE) {
    // ===== sms[h] = Wms[h] . ms ===== (wave per head)
    const float* wr = Wms + wv * HID;
    float a = 0.f;
#pragma unroll
    for (int m = 0; m < 4; ++m) a = fmaf(wr[ln + 64 * m], ms[ln + 64 * m], a);
    a = redw(a);
    if (ln == 0) sms[wv] = a;
  } else if (bid < SCAN_BASE) {
    // ===== pre1 rows [16q, 16q+16) =====
    const int q = bid - PRE1_BASE;
    const int dist = dist_p[0];
    for (int rr = 0; rr < 2; ++rr) {
      int r = q * 16 + wv * 2 + rr;
      const float* w = W1 + (size_t)r * FDIM;
      float a = 0.f;
#pragma unroll
      for (int m = 0; m < 4; ++m) a = fmaf(w[ln + 64 * m], ms[ln + 64 * m], a);
      a = fmaf(w[320 + ln], demb_h[(size_t)dist * D_EMB + ln], a);
      a = redw(a);
      if (ln == 0) pre1[r] = a + b1[r];
    }
  } else {
    // ===== scan-only =====
    do_scan(etrg, esrc, ebin, NSTAGE + (bid - SCAN_BASE), tid, nE, li, ld,
            count, m_src, m_trg, m_bin);
  }
  block_release_add(flag_scan);
}

extern "C" void kernel_launch(void* const* d_in, const int* in_sizes, int n_in,
                              void* d_out, int out_size, void* d_ws, size_t ws_size,
                              hipStream_t stream) {
  const float* nf     = (const float*)d_in[0];
  const int*   esrc   = (const int*)d_in[1];
  const int*   etrg   = (const int*)d_in[2];
  const int*   ebin   = (const int*)d_in[3];
  const float* ms     = (const float*)d_in[4];
  const int*   li_p   = (const int*)d_in[5];
  const int*   ld_p   = (const int*)d_in[6];
  const int*   dist_p = (const int*)d_in[7];
  const float* Wproj  = (const float*)d_in[8];
  const float* a_src  = (const float*)d_in[9];
  const float* a_trg  = (const float*)d_in[10];
  const float* Wms    = (const float*)d_in[11];
  const float* demb_g = (const float*)d_in[12];
  const float* Wdist  = (const float*)d_in[13];
  const float* Wskip  = (const float*)d_in[14];
  const float* gbias  = (const float*)d_in[15];
  const float* demb_h = (const float*)d_in[16];
  const float* W1     = (const float*)d_in[17];
  const float* b1     = (const float*)d_in[18];
  const float* W2     = (const float*)d_in[19];
  const float* b2     = (const float*)d_in[20];
  const int nE = in_sizes[1];

  int*   ws_i = (int*)d_ws;
  float* fb   = (float*)d_ws + 512;

  hipMemsetAsync(d_ws, 0, 64, stream);  // count + flags

  fused_k<<<GRID, 512, 0, stream>>>(
      nf, esrc, etrg, ebin, ms, li_p, ld_p, dist_p,
      Wproj, a_src, a_trg, Wms, demb_g, Wdist, Wskip, gbias, demb_h,
      W1, b1, W2, b2, nE, ws_i, fb, (float*)d_out);
}

// Round 7
// 32.081 us; speedup vs baseline: 1.7539x; 1.7539x over previous
//
#include <hip/hip_runtime.h>
#include <hip/hip_bf16.h>
#include <math.h>

#define D_IN  128
#define NH    8
#define F_OUT 32
#define HID   256
#define D_EMB 64
#define BINS  200
#define FDIM  384
#define CAP   128

#define NSTAGE    32
#define VSRC_BASE 32   // 8 blocks: vsrc + strg
#define SKIP_BASE 40   // 8 blocks: skipb
#define ESC_BASE  48   // 4 blocks: escall
#define SMS_BID   52   // 1 block : sms
#define PRE1_BASE 53   // 16 blocks: pre1
#define SCAN_BASE 69   // rest scan-only
#define GRID      256
#define NSCAN     (NSTAGE + (GRID - SCAN_BASE))   // 219 scanning blocks

#define AR __ATOMIC_RELAXED
#define SA __HIP_MEMORY_SCOPE_AGENT
// relaxed agent-scope ops: sc1 write-through / read-through at the coherent
// point (Infinity Cache). NO acquire/release fences anywhere -> no L2
// writeback (wbl2) / invalidate (inv) storms across XCDs.
#define STF(p, v) __hip_atomic_store((p), (v), AR, SA)
#define LDF(p)    __hip_atomic_load((p), AR, SA)

__device__ __forceinline__ float redw(float v) {
#pragma unroll
  for (int o = 32; o > 0; o >>= 1) v += __shfl_down(v, o, 64);
  return v;
}

__device__ __forceinline__ void vm0() {
  asm volatile("s_waitcnt vmcnt(0)" ::: "memory");   // stores acked at IC
}

__device__ __forceinline__ void release_flag(int* flag) {
  vm0();                 // each thread: its sc1 stores complete
  __syncthreads();       // all waves of the block done
  if (threadIdx.x == 0) __hip_atomic_fetch_add(flag, 1, AR, SA);
}

__device__ __forceinline__ void wait_flag(int* flag, int target) {
  if (threadIdx.x == 0)
    while (__hip_atomic_load(flag, AR, SA) < target) __builtin_amdgcn_s_sleep(2);
  __syncthreads();
}

__device__ __forceinline__ void do_scan(const int* __restrict__ etrg,
                                        const int* __restrict__ esrc,
                                        const int* __restrict__ ebin,
                                        int sid, int tid, int nE, int li, int ld,
                                        int* count, int* m_src, int* m_trg, int* m_bin) {
  const int gid = sid * 512 + tid;
  const int stride = NSCAN * 512;
  const int nE4 = nE >> 2;
  const int4* t4 = (const int4*)etrg;
  for (int e4 = gid; e4 < nE4; e4 += stride) {
    int4 t = t4[e4];
    int ev[4] = {t.x, t.y, t.z, t.w};
#pragma unroll
    for (int k = 0; k < 4; ++k) {
      if (ev[k] == li || ev[k] == ld) {
        int e = e4 * 4 + k;
        int pos = atomicAdd(count, 1);
        if (pos < CAP) {
          STF(m_src + pos, esrc[e]);
          STF(m_trg + pos, ev[k]);
          STF(m_bin + pos, ebin[e]);
        }
      }
    }
  }
  if (sid == NSTAGE && tid == 0) {   // tail (nE % 4)
    for (int e = nE4 * 4; e < nE; ++e) {
      int tv = etrg[e];
      if (tv == li || tv == ld) {
        int pos = atomicAdd(count, 1);
        if (pos < CAP) { STF(m_src + pos, esrc[e]); STF(m_trg + pos, tv); STF(m_bin + pos, ebin[e]); }
      }
    }
  }
}

__global__ __launch_bounds__(512, 1) void fused_k(
    const float* __restrict__ nf, const int* __restrict__ esrc,
    const int* __restrict__ etrg, const int* __restrict__ ebin,
    const float* __restrict__ ms, const int* __restrict__ li_p,
    const int* __restrict__ ld_p, const int* __restrict__ dist_p,
    const float* __restrict__ Wproj, const float* __restrict__ a_src,
    const float* __restrict__ a_trg, const float* __restrict__ Wms,
    const float* __restrict__ demb_g, const float* __restrict__ Wdist,
    const float* __restrict__ Wskip, const float* __restrict__ gbias,
    const float* __restrict__ demb_h, const float* __restrict__ W1,
    const float* __restrict__ b1, const float* __restrict__ W2,
    const float* __restrict__ b2, int nE,
    int* __restrict__ ws_i, float* __restrict__ fb, float* __restrict__ out) {
  int* count     = ws_i;
  int* flag_scan = ws_i + 1;
  int* flag_proj = ws_i + 2;
  int* flag_mlp  = ws_i + 3;
  int* m_src     = ws_i + 16;
  int* m_trg     = m_src + CAP;
  int* m_bin     = m_trg + CAP;
  float* vsrc    = fb;               // 1024
  float* strg    = fb + 1024;        // 16
  float* sms     = fb + 1040;        // 8
  float* escall  = fb + 1048;        // 1600
  float* skipb   = fb + 2648;        // 512
  float* pre1    = fb + 3160;        // 256
  float* out_ws  = fb + 3416;        // 512
  float* partial = fb + 3928;        // 32

  __shared__ int   s_es[CAP], s_tb[CAP], s_bn[CAP];
  __shared__ float s_p[CAP];
  __shared__ float s_den[2];
  __shared__ __align__(16) float s_vs[D_IN];
  __shared__ __align__(16) float s_agg[2][D_IN];
  __shared__ __align__(16) float s_out[512];
  __shared__ __align__(16) float s_emb[64];
  __shared__ float s_pr[8];
  __shared__ __align__(16) float s_nf2[2 * D_IN];
  __shared__ __align__(16) float s_vp[2][4][D_IN];

  const int bid = blockIdx.x, tid = threadIdx.x;
  const int wv = tid >> 6, ln = tid & 63;
  const int li = li_p[0], ld = ld_p[0];

  if (bid < NSTAGE) {
    // ===================== STAGE block =====================
    const int k = bid;
    const int h = k >> 2;            // head this block serves
    const int row = k * 8 + wv;      // this wave's output row
    // register preload (read-only inputs; issued at t=0, normal cached loads)
    const float wpA = Wproj[row * D_IN + ln * 2];
    const float wpB = Wproj[row * D_IN + ln * 2 + 1];
    const float w1e = W1[(size_t)row * FDIM + HID + ln];
    const float w2v = W2[row];

    do_scan(etrg, esrc, ebin, k, tid, nE, li, ld, count, m_src, m_trg, m_bin);
    release_flag(flag_scan);
    wait_flag(flag_scan, GRID);

    // ---- proj phase: scores -> attn -> agg(head h) -> own 8 rows ----
    int cnt = LDF(count); if (cnt > CAP) cnt = CAP;
    if (tid < cnt) {
      s_es[tid] = LDF(m_src + tid);
      s_tb[tid] = (LDF(m_trg + tid) == li) ? 0 : 1;
      s_bn[tid] = LDF(m_bin + tid);
    }
    if (tid < D_IN) s_vs[tid] = LDF(vsrc + h * D_IN + tid);
    __syncthreads();
    const float sms_h = LDF(sms + h);
    const float strg0 = LDF(strg + h), strg1 = LDF(strg + NH + h);
    for (int e = wv; e < cnt; e += 8) {       // wave per edge
      const float* nfr = nf + (size_t)s_es[e] * D_IN + ln * 2;
      float part = nfr[0] * s_vs[ln * 2] + nfr[1] * s_vs[ln * 2 + 1];
      part = redw(part);
      if (ln == 0) {
        float sc = part + (s_tb[e] ? strg1 : strg0) + sms_h + LDF(escall + s_bn[e] * NH + h);
        sc = sc > 0.f ? sc : 0.2f * sc;       // leaky_relu(0.2); global max cancels
        s_p[e] = expf(sc);
      }
    }
    __syncthreads();
    if (tid < 2) {
      float d = 1e-16f;
      for (int e = 0; e < cnt; ++e) if (s_tb[e] == (int)tid) d += s_p[e];
      s_den[tid] = d;
    }
    __syncthreads();
    if (tid < cnt) s_p[tid] = s_p[tid] / s_den[s_tb[tid]];
    __syncthreads();
    if (tid < 256) {                          // agg[t,d] for head h
      const int t = tid >> 7, d = tid & 127;
      float a = 0.f;
      for (int e = 0; e < cnt; ++e)
        if (s_tb[e] == t) a = fmaf(s_p[e], nf[(size_t)s_es[e] * D_IN + d], a);
      s_agg[t][d] = a;
    }
    __syncthreads();
    {
      float o0 = wpA * s_agg[0][ln * 2] + wpB * s_agg[0][ln * 2 + 1];
      float o1 = wpA * s_agg[1][ln * 2] + wpB * s_agg[1][ln * 2 + 1];
      o0 = redw(o0); o1 = redw(o1);
      if (ln == 0) {
        STF(out_ws + row,       o0 + LDF(skipb + row));
        STF(out_ws + 256 + row, o1 + LDF(skipb + 256 + row));
      }
    }
    release_flag(flag_proj);
    wait_flag(flag_proj, NSTAGE);

    // ---- MLP phase: emb (redundant, cheap) + own 8 rows from registers ----
    s_out[tid] = LDF(out_ws + tid);
    __syncthreads();
    if (tid < 64) {
      const int t = tid >> 5, f = tid & 31;
      float s = 0.f;
#pragma unroll
      for (int hh = 0; hh < NH; ++hh) s += s_out[t * 256 + hh * F_OUT + f];
      s = s * 0.125f + gbias[f];
      s_emb[tid] = s > 0.f ? s : expm1f(s);   // ELU
    }
    __syncthreads();
    {
      float acc = redw(w1e * s_emb[ln]);
      if (ln == 0) {
        float h1 = fmaxf(LDF(pre1 + row) + acc, 0.f);
        s_pr[wv] = w2v * h1;
      }
    }
    __syncthreads();
    if (tid == 0) {
      float bp = 0.f;
#pragma unroll
      for (int w = 0; w < 8; ++w) bp += s_pr[w];
      STF(partial + k, bp);
      vm0();
      int ret = __hip_atomic_fetch_add(flag_mlp, 1, AR, SA);
      if (ret == NSTAGE - 1) {               // last block finalizes
        float s = b2[0];
        for (int j = 0; j < NSTAGE; ++j) s += LDF(partial + j);
        out[0] = s;
      }
    }
    return;
  }

  if (bid < SKIP_BASE) {
    // ===== vsrc + strg for head h =====
    const int h = bid - VSRC_BASE;
    const int d = tid & 127, fg = tid >> 7;
    float as = 0.f, at = 0.f;
    for (int f = fg * 8; f < fg * 8 + 8; ++f) {
      float w = Wproj[(h * F_OUT + f) * D_IN + d];
      as = fmaf(a_src[h * F_OUT + f], w, as);
      at = fmaf(a_trg[h * F_OUT + f], w, at);
    }
    s_vp[0][fg][d] = as; s_vp[1][fg][d] = at;
    __syncthreads();
    if (tid < 128)
      STF(vsrc + h * D_IN + tid,
          s_vp[0][0][tid] + s_vp[0][1][tid] + s_vp[0][2][tid] + s_vp[0][3][tid]);
    if (tid >= 128 && tid < 256) {
      int dd = tid - 128;
      s_vp[1][0][dd] = s_vp[1][0][dd] + s_vp[1][1][dd] + s_vp[1][2][dd] + s_vp[1][3][dd];
    }
    if (tid >= 256 && tid < 320) {
      int j = tid - 256;
      ((float4*)s_nf2)[j] = ((const float4*)(nf + (size_t)(j < 32 ? li : ld) * D_IN))[j & 31];
    }
    __syncthreads();
    if (wv < 2) {                             // strg[t,h] = nf2[t] . vtrg[h]
      float part = s_nf2[wv * D_IN + ln * 2] * s_vp[1][0][ln * 2]
                 + s_nf2[wv * D_IN + ln * 2 + 1] * s_vp[1][0][ln * 2 + 1];
      part = redw(part);
      if (ln == 0) STF(strg + wv * NH + h, part);
    }
  } else if (bid < ESC_BASE) {
    // ===== skipb rows [32p, 32p+32) =====
    const int base = (bid - SKIP_BASE) * 32;
    if (tid < 64)
      ((float4*)s_nf2)[tid] = ((const float4*)(nf + (size_t)(tid < 32 ? li : ld) * D_IN))[tid & 31];
    __syncthreads();
    for (int rd = 0; rd < 4; ++rd) {
      int r = base + rd * 8 + wv;
      float w0 = Wskip[r * D_IN + ln * 2], w1 = Wskip[r * D_IN + ln * 2 + 1];
      float o0 = w0 * s_nf2[ln * 2] + w1 * s_nf2[ln * 2 + 1];
      float o1 = w0 * s_nf2[D_IN + ln * 2] + w1 * s_nf2[D_IN + ln * 2 + 1];
      o0 = redw(o0); o1 = redw(o1);
      if (ln == 0) { STF(skipb + r, o0); STF(skipb + 256 + r, o1); }
    }
  } else if (bid < SMS_BID) {
    // ===== escall bins [50p, 50p+50) =====
    const int p = bid - ESC_BASE;
    const int g = tid >> 3, l8 = tid & 7;
    for (int it = g; it < 50 * NH; it += 64) {
      int bin = p * 50 + (it >> 3), hh = it & 7;
      const float* de = demb_g + bin * D_EMB + l8 * 8;
      const float* wd = Wdist + hh * D_EMB + l8 * 8;
      float a = 0.f;
#pragma unroll
      for (int j = 0; j < 8; ++j) a = fmaf(de[j], wd[j], a);
#pragma unroll
      for (int o = 4; o > 0; o >>= 1) a += __shfl_down(a, o, 8);
      if (l8 == 0) STF(escall + bin * NH + hh, a);
    }
  } else if (bid < PRE1_BASE) {
    // ===== sms[h] = Wms[h] . ms (wave per head) =====
    const float* wr = Wms + wv * HID;
    float a = 0.f;
#pragma unroll
    for (int m = 0; m < 4; ++m) a = fmaf(wr[ln + 64 * m], ms[ln + 64 * m], a);
    a = redw(a);
    if (ln == 0) STF(sms + wv, a);
  } else if (bid < SCAN_BASE) {
    // ===== pre1 rows [16q, 16q+16) =====
    const int q = bid - PRE1_BASE;
    const int dist = dist_p[0];
    for (int rr = 0; rr < 2; ++rr) {
      int r = q * 16 + wv * 2 + rr;
      const float* w = W1 + (size_t)r * FDIM;
      float a = 0.f;
#pragma unroll
      for (int m = 0; m < 4; ++m) a = fmaf(w[ln + 64 * m], ms[ln + 64 * m], a);
      a = fmaf(w[320 + ln], demb_h[(size_t)dist * D_EMB + ln], a);
      a = redw(a);
      if (ln == 0) STF(pre1 + r, a + b1[r]);
    }
  } else {
    // ===== scan-only =====
    do_scan(etrg, esrc, ebin, NSTAGE + (bid - SCAN_BASE), tid, nE, li, ld,
            count, m_src, m_trg, m_bin);
  }
  release_flag(flag_scan);
}

extern "C" void kernel_launch(void* const* d_in, const int* in_sizes, int n_in,
                              void* d_out, int out_size, void* d_ws, size_t ws_size,
                              hipStream_t stream) {
  const float* nf     = (const float*)d_in[0];
  const int*   esrc   = (const int*)d_in[1];
  const int*   etrg   = (const int*)d_in[2];
  const int*   ebin   = (const int*)d_in[3];
  const float* ms     = (const float*)d_in[4];
  const int*   li_p   = (const int*)d_in[5];
  const int*   ld_p   = (const int*)d_in[6];
  const int*   dist_p = (const int*)d_in[7];
  const float* Wproj  = (const float*)d_in[8];
  const float* a_src  = (const float*)d_in[9];
  const float* a_trg  = (const float*)d_in[10];
  const float* Wms    = (const float*)d_in[11];
  const float* demb_g = (const float*)d_in[12];
  const float* Wdist  = (const float*)d_in[13];
  const float* Wskip  = (const float*)d_in[14];
  const float* gbias  = (const float*)d_in[15];
  const float* demb_h = (const float*)d_in[16];
  const float* W1     = (const float*)d_in[17];
  const float* b1     = (const float*)d_in[18];
  const float* W2     = (const float*)d_in[19];
  const float* b2     = (const float*)d_in[20];
  const int nE = in_sizes[1];

  int*   ws_i = (int*)d_ws;
  float* fb   = (float*)d_ws + 512;

  hipMemsetAsync(d_ws, 0, 64, stream);  // count + flags

  fused_k<<<GRID, 512, 0, stream>>>(
      nf, esrc, etrg, ebin, ms, li_p, ld_p, dist_p,
      Wproj, a_src, a_trg, Wms, demb_g, Wdist, Wskip, gbias, demb_h,
      W1, b1, W2, b2, nE, ws_i, fb, (float*)d_out);
}

// Round 8
// 28.275 us; speedup vs baseline: 1.9900x; 1.1346x over previous
//
#include <hip/hip_runtime.h>
#include <hip/hip_bf16.h>
#include <math.h>

#define D_IN  128
#define NH    8
#define F_OUT 32
#define HID   256
#define D_EMB 64
#define BINS  200
#define FDIM  384
#define CAP   128

// ---- K1 grid layout (256 blocks) ----
#define NSCAN  219
#define VSRC_B 219   // 8 blocks : vsrc + strg
#define SKIP_B 227   // 8 blocks : skipb
#define ESC_B  235   // 4 blocks : escall
#define SMS_B  239   // 1 block  : sms
#define PRE1_B 240   // 16 blocks: pre1  -> 256
#define K1GRID 256

// ---- K2 ----
#define K2GRID 32

#define AR __ATOMIC_RELAXED
#define SA __HIP_MEMORY_SCOPE_AGENT
#define STF(p, v) __hip_atomic_store((p), (v), AR, SA)
#define LDF(p)    __hip_atomic_load((p), AR, SA)

// ws ints: [0]=count [1]=flag_proj [2]=flag_mlp ; [16..) m_src[CAP] m_trg[CAP] m_bin[CAP]
// ws floats (base 512): vsrc[1024] strg[16] sms[8] escall[1600] skipb[512] pre1[256]
//                       out_ws[512] partial[32]

__device__ __forceinline__ float redw(float v) {
#pragma unroll
  for (int o = 32; o > 0; o >>= 1) v += __shfl_down(v, o, 64);
  return v;
}

__device__ __forceinline__ void vm0() {
  asm volatile("s_waitcnt vmcnt(0)" ::: "memory");
}

// =====================================================================
// K1: edge scan + all scan-independent precomputation. No flags at all;
// kernel-boundary release/acquire publishes everything to K2.
// =====================================================================
__global__ __launch_bounds__(512, 1) void scan_pre_k(
    const float* __restrict__ nf, const int* __restrict__ esrc,
    const int* __restrict__ etrg, const int* __restrict__ ebin,
    const float* __restrict__ ms, const int* __restrict__ li_p,
    const int* __restrict__ ld_p, const int* __restrict__ dist_p,
    const float* __restrict__ Wproj, const float* __restrict__ a_src,
    const float* __restrict__ a_trg, const float* __restrict__ Wms,
    const float* __restrict__ demb_g, const float* __restrict__ Wdist,
    const float* __restrict__ Wskip, const float* __restrict__ W1,
    const float* __restrict__ b1, const float* __restrict__ demb_h,
    int nE, int* __restrict__ ws_i, float* __restrict__ fb) {
  int* count  = ws_i;
  int* m_src  = ws_i + 16;
  int* m_trg  = m_src + CAP;
  int* m_bin  = m_trg + CAP;
  float* vsrc   = fb;
  float* strg   = fb + 1024;
  float* sms    = fb + 1040;
  float* escall = fb + 1048;
  float* skipb  = fb + 2648;
  float* pre1   = fb + 3160;

  __shared__ __align__(16) float s_nf2[2 * D_IN];
  __shared__ __align__(16) float s_vp[2][4][D_IN];

  const int bid = blockIdx.x, tid = threadIdx.x;
  const int wv = tid >> 6, ln = tid & 63;
  const int li = li_p[0], ld = ld_p[0];

  if (bid < NSCAN) {
    // ===== edge scan =====
    const int gid = bid * 512 + tid;
    const int stride = NSCAN * 512;
    const int nE4 = nE >> 2;
    const int4* t4 = (const int4*)etrg;
    for (int e4 = gid; e4 < nE4; e4 += stride) {
      int4 t = t4[e4];
      int ev[4] = {t.x, t.y, t.z, t.w};
#pragma unroll
      for (int k = 0; k < 4; ++k) {
        if (ev[k] == li || ev[k] == ld) {
          int e = e4 * 4 + k;
          int pos = atomicAdd(count, 1);
          if (pos < CAP) { m_src[pos] = esrc[e]; m_trg[pos] = ev[k]; m_bin[pos] = ebin[e]; }
        }
      }
    }
    if (gid == 0) {  // tail (nE % 4)
      for (int e = nE4 * 4; e < nE; ++e) {
        int tv = etrg[e];
        if (tv == li || tv == ld) {
          int pos = atomicAdd(count, 1);
          if (pos < CAP) { m_src[pos] = esrc[e]; m_trg[pos] = tv; m_bin[pos] = ebin[e]; }
        }
      }
    }
  } else if (bid < SKIP_B) {
    // ===== vsrc + strg for head h =====
    const int h = bid - VSRC_B;
    const int d = tid & 127, fg = tid >> 7;
    float as = 0.f, at = 0.f;
    for (int f = fg * 8; f < fg * 8 + 8; ++f) {
      float w = Wproj[(h * F_OUT + f) * D_IN + d];
      as = fmaf(a_src[h * F_OUT + f], w, as);
      at = fmaf(a_trg[h * F_OUT + f], w, at);
    }
    s_vp[0][fg][d] = as; s_vp[1][fg][d] = at;
    __syncthreads();
    if (tid < 128)
      vsrc[h * D_IN + tid] =
          s_vp[0][0][tid] + s_vp[0][1][tid] + s_vp[0][2][tid] + s_vp[0][3][tid];
    if (tid >= 128 && tid < 256) {
      int dd = tid - 128;
      s_vp[1][0][dd] = s_vp[1][0][dd] + s_vp[1][1][dd] + s_vp[1][2][dd] + s_vp[1][3][dd];
    }
    if (tid >= 256 && tid < 320) {
      int j = tid - 256;
      ((float4*)s_nf2)[j] = ((const float4*)(nf + (size_t)(j < 32 ? li : ld) * D_IN))[j & 31];
    }
    __syncthreads();
    if (wv < 2) {   // strg[t,h] = nf2[t] . vtrg[h]
      float part = s_nf2[wv * D_IN + ln * 2] * s_vp[1][0][ln * 2]
                 + s_nf2[wv * D_IN + ln * 2 + 1] * s_vp[1][0][ln * 2 + 1];
      part = redw(part);
      if (ln == 0) strg[wv * NH + h] = part;
    }
  } else if (bid < ESC_B) {
    // ===== skipb rows [32p, 32p+32) =====
    const int base = (bid - SKIP_B) * 32;
    if (tid < 64)
      ((float4*)s_nf2)[tid] = ((const float4*)(nf + (size_t)(tid < 32 ? li : ld) * D_IN))[tid & 31];
    __syncthreads();
    for (int rd = 0; rd < 4; ++rd) {
      int r = base + rd * 8 + wv;
      float w0 = Wskip[r * D_IN + ln * 2], w1 = Wskip[r * D_IN + ln * 2 + 1];
      float o0 = w0 * s_nf2[ln * 2] + w1 * s_nf2[ln * 2 + 1];
      float o1 = w0 * s_nf2[D_IN + ln * 2] + w1 * s_nf2[D_IN + ln * 2 + 1];
      o0 = redw(o0); o1 = redw(o1);
      if (ln == 0) { skipb[r] = o0; skipb[256 + r] = o1; }
    }
  } else if (bid < SMS_B) {
    // ===== escall bins [50p, 50p+50) =====
    const int p = bid - ESC_B;
    const int g = tid >> 3, l8 = tid & 7;
    for (int it = g; it < 50 * NH; it += 64) {
      int bin = p * 50 + (it >> 3), hh = it & 7;
      const float* de = demb_g + bin * D_EMB + l8 * 8;
      const float* wd = Wdist + hh * D_EMB + l8 * 8;
      float a = 0.f;
#pragma unroll
      for (int j = 0; j < 8; ++j) a = fmaf(de[j], wd[j], a);
#pragma unroll
      for (int o = 4; o > 0; o >>= 1) a += __shfl_down(a, o, 8);
      if (l8 == 0) escall[bin * NH + hh] = a;
    }
  } else if (bid < PRE1_B) {
    // ===== sms[h] = Wms[h] . ms (wave per head) =====
    const float* wr = Wms + wv * HID;
    float a = 0.f;
#pragma unroll
    for (int m = 0; m < 4; ++m) a = fmaf(wr[ln + 64 * m], ms[ln + 64 * m], a);
    a = redw(a);
    if (ln == 0) sms[wv] = a;
  } else {
    // ===== pre1 rows [16q, 16q+16) =====
    const int q = bid - PRE1_B;
    const int dist = dist_p[0];
    for (int rr = 0; rr < 2; ++rr) {
      int r = q * 16 + wv * 2 + rr;
      const float* w = W1 + (size_t)r * FDIM;
      float a = 0.f;
#pragma unroll
      for (int m = 0; m < 4; ++m) a = fmaf(w[ln + 64 * m], ms[ln + 64 * m], a);
      a = fmaf(w[320 + ln], demb_h[(size_t)dist * D_EMB + ln], a);
      a = redw(a);
      if (ln == 0) pre1[r] = a + b1[r];
    }
  }
}

// =====================================================================
// K2: 32 blocks; block k owns output rows [8k, 8k+8) and head k>>2.
// Two lightweight 32-way relaxed-flag syncs only.
// =====================================================================
__global__ __launch_bounds__(512, 1) void finalize_k(
    const float* __restrict__ nf,
    const int* __restrict__ li_p, const int* __restrict__ ld_p,
    const float* __restrict__ Wproj, const float* __restrict__ gbias,
    const float* __restrict__ W1, const float* __restrict__ W2,
    const float* __restrict__ b2,
    int* __restrict__ ws_i, float* __restrict__ fb, float* __restrict__ out) {
  int* count     = ws_i;
  int* flag_proj = ws_i + 1;
  int* flag_mlp  = ws_i + 2;
  int* m_src     = ws_i + 16;
  int* m_trg     = m_src + CAP;
  int* m_bin     = m_trg + CAP;
  float* vsrc    = fb;
  float* strg    = fb + 1024;
  float* sms     = fb + 1040;
  float* escall  = fb + 1048;
  float* skipb   = fb + 2648;
  float* pre1    = fb + 3160;
  float* out_ws  = fb + 3416;
  float* partial = fb + 3928;

  __shared__ int   s_es[CAP], s_tb[CAP], s_bn[CAP];
  __shared__ float s_p[CAP];
  __shared__ float s_den[2];
  __shared__ __align__(16) float s_vs[D_IN];
  __shared__ __align__(16) float s_agg[2][D_IN];
  __shared__ __align__(16) float s_out[512];
  __shared__ __align__(16) float s_emb[64];
  __shared__ float s_pr[8];

  const int k = blockIdx.x, tid = threadIdx.x;
  const int wv = tid >> 6, ln = tid & 63;
  const int li = li_p[0], ld = ld_p[0];
  const int h = k >> 2;
  const int row = k * 8 + wv;

  // register preload (plain cached loads; K1 products visible via kernel boundary)
  const float wpA = Wproj[row * D_IN + ln * 2];
  const float wpB = Wproj[row * D_IN + ln * 2 + 1];
  const float w1e = W1[(size_t)row * FDIM + HID + ln];
  const float w2v = W2[row];

  int cnt = *count; if (cnt > CAP) cnt = CAP;
  if (tid < cnt) {
    s_es[tid] = m_src[tid];
    s_tb[tid] = (m_trg[tid] == li) ? 0 : 1;
    s_bn[tid] = m_bin[tid];
  }
  if (tid < D_IN) s_vs[tid] = vsrc[h * D_IN + tid];
  __syncthreads();
  const float sms_h = sms[h], strg0 = strg[h], strg1 = strg[NH + h];

  // scores: exp(leaky_relu(.)) ; reference's global max cancels in exp_s/denom
  for (int e = wv; e < cnt; e += 8) {
    const float* nfr = nf + (size_t)s_es[e] * D_IN + ln * 2;
    float part = nfr[0] * s_vs[ln * 2] + nfr[1] * s_vs[ln * 2 + 1];
    part = redw(part);
    if (ln == 0) {
      float sc = part + (s_tb[e] ? strg1 : strg0) + sms_h + escall[s_bn[e] * NH + h];
      sc = sc > 0.f ? sc : 0.2f * sc;
      s_p[e] = expf(sc);
    }
  }
  __syncthreads();
  if (tid < 2) {
    float d = 1e-16f;
    for (int e = 0; e < cnt; ++e) if (s_tb[e] == (int)tid) d += s_p[e];
    s_den[tid] = d;
  }
  __syncthreads();
  if (tid < cnt) s_p[tid] = s_p[tid] / s_den[s_tb[tid]];
  __syncthreads();
  if (tid < 256) {                 // agg[t,d] for head h (nf L1-warm from scores)
    const int t = tid >> 7, d = tid & 127;
    float a = 0.f;
    for (int e = 0; e < cnt; ++e)
      if (s_tb[e] == t) a = fmaf(s_p[e], nf[(size_t)s_es[e] * D_IN + d], a);
    s_agg[t][d] = a;
  }
  __syncthreads();
  {
    float o0 = wpA * s_agg[0][ln * 2] + wpB * s_agg[0][ln * 2 + 1];
    float o1 = wpA * s_agg[1][ln * 2] + wpB * s_agg[1][ln * 2 + 1];
    o0 = redw(o0); o1 = redw(o1);
    if (ln == 0) {
      STF(out_ws + row,       o0 + skipb[row]);
      STF(out_ws + 256 + row, o1 + skipb[256 + row]);
    }
  }
  // ---- 32-way proj barrier (relaxed flags; no fences) ----
  vm0();
  __syncthreads();
  if (tid == 0) {
    __hip_atomic_fetch_add(flag_proj, 1, AR, SA);
    while (LDF(flag_proj) < K2GRID) __builtin_amdgcn_s_sleep(1);
  }
  __syncthreads();

  // ---- MLP phase ----
  s_out[tid] = LDF(out_ws + tid);
  __syncthreads();
  if (tid < 64) {
    const int t = tid >> 5, f = tid & 31;
    float s = 0.f;
#pragma unroll
    for (int hh = 0; hh < NH; ++hh) s += s_out[t * 256 + hh * F_OUT + f];
    s = s * 0.125f + gbias[f];
    s_emb[tid] = s > 0.f ? s : expm1f(s);   // ELU
  }
  __syncthreads();
  {
    float acc = redw(w1e * s_emb[ln]);
    if (ln == 0) {
      float h1 = fmaxf(pre1[row] + acc, 0.f);
      s_pr[wv] = w2v * h1;
    }
  }
  __syncthreads();
  if (tid == 0) {
    float bp = 0.f;
#pragma unroll
    for (int w = 0; w < 8; ++w) bp += s_pr[w];
    STF(partial + k, bp);
    vm0();
    int ret = __hip_atomic_fetch_add(flag_mlp, 1, AR, SA);
    if (ret == K2GRID - 1) {       // last block finalizes
      float s = b2[0];
      for (int j = 0; j < K2GRID; ++j) s += LDF(partial + j);
      out[0] = s;
    }
  }
}

extern "C" void kernel_launch(void* const* d_in, const int* in_sizes, int n_in,
                              void* d_out, int out_size, void* d_ws, size_t ws_size,
                              hipStream_t stream) {
  const float* nf     = (const float*)d_in[0];
  const int*   esrc   = (const int*)d_in[1];
  const int*   etrg   = (const int*)d_in[2];
  const int*   ebin   = (const int*)d_in[3];
  const float* ms     = (const float*)d_in[4];
  const int*   li_p   = (const int*)d_in[5];
  const int*   ld_p   = (const int*)d_in[6];
  const int*   dist_p = (const int*)d_in[7];
  const float* Wproj  = (const float*)d_in[8];
  const float* a_src  = (const float*)d_in[9];
  const float* a_trg  = (const float*)d_in[10];
  const float* Wms    = (const float*)d_in[11];
  const float* demb_g = (const float*)d_in[12];
  const float* Wdist  = (const float*)d_in[13];
  const float* Wskip  = (const float*)d_in[14];
  const float* gbias  = (const float*)d_in[15];
  const float* demb_h = (const float*)d_in[16];
  const float* W1     = (const float*)d_in[17];
  const float* b1     = (const float*)d_in[18];
  const float* W2     = (const float*)d_in[19];
  const float* b2     = (const float*)d_in[20];
  const int nE = in_sizes[1];

  int*   ws_i = (int*)d_ws;
  float* fb   = (float*)d_ws + 512;

  hipMemsetAsync(d_ws, 0, 64, stream);  // count + flags

  scan_pre_k<<<K1GRID, 512, 0, stream>>>(
      nf, esrc, etrg, ebin, ms, li_p, ld_p, dist_p,
      Wproj, a_src, a_trg, Wms, demb_g, Wdist, Wskip, W1, b1, demb_h,
      nE, ws_i, fb);

  finalize_k<<<K2GRID, 512, 0, stream>>>(
      nf, li_p, ld_p, Wproj, gbias, W1, W2, b2, ws_i, fb, (float*)d_out);
}

// Round 9
// 26.646 us; speedup vs baseline: 2.1117x; 1.0611x over previous
//
#include <hip/hip_runtime.h>
#include <hip/hip_bf16.h>
#include <math.h>

#define D_IN  128
#define NH    8
#define F_OUT 32
#define HID   256
#define D_EMB 64
#define BINS  200
#define FDIM  384
#define CAP   128
#define SLOTS 6

// ---- K1 grid (256 blocks): 219 scan + 37 pre ----
#define NSCANB 219
#define VSRC_B 219   // 8 blocks : vsrc + strg   (block 219 also zeroes K2 flags)
#define SKIP_B 227   // 8 blocks : skipb
#define ESC_B  235   // 4 blocks : escall
#define SMS_B  239   // 1 block  : sms
#define PRE1_B 240   // 16 blocks: pre1 -> 256
#define K1GRID 256
#define K2GRID 32

#define AR __ATOMIC_RELAXED
#define SA __HIP_MEMORY_SCOPE_AGENT
#define STF(p, v) __hip_atomic_store((p), (v), AR, SA)
#define LDF(p)    __hip_atomic_load((p), AR, SA)

// ---- ws layout ----
// ints (ws_i): [0]=flag_proj [1]=flag_mlp
//   bcnt:  +16   (219)
//   bsrc:  +256  (219*6=1314)
//   btrg:  +1600 (1314)
//   bbin:  +2944 (1314)
// floats (fb = (float*)d_ws + 8192):
//   vsrc[1024] strg[16] sms[8] escall[1600] skipb[512] pre1[256]
//   out_ws[512] partial[32]   (ends 3960)
//   bnf: fb + 4096  (219*6*128 floats, dense nf rows of matched edges)

__device__ __forceinline__ float redw(float v) {
#pragma unroll
  for (int o = 32; o > 0; o >>= 1) v += __shfl_down(v, o, 64);
  return v;
}

__device__ __forceinline__ void vm0() {
  asm volatile("s_waitcnt vmcnt(0)" ::: "memory");
}

// =====================================================================
// K1: edge scan (private per-block slots, no global count) + pre-tasks.
// No atomics to global, no flags; kernel boundary publishes to K2.
// =====================================================================
__global__ __launch_bounds__(512, 1) void scan_pre_k(
    const float* __restrict__ nf, const int* __restrict__ esrc,
    const int* __restrict__ etrg, const int* __restrict__ ebin,
    const float* __restrict__ ms, const int* __restrict__ li_p,
    const int* __restrict__ ld_p, const int* __restrict__ dist_p,
    const float* __restrict__ Wproj, const float* __restrict__ a_src,
    const float* __restrict__ a_trg, const float* __restrict__ Wms,
    const float* __restrict__ demb_g, const float* __restrict__ Wdist,
    const float* __restrict__ Wskip, const float* __restrict__ W1,
    const float* __restrict__ b1, const float* __restrict__ demb_h,
    int nE, int* __restrict__ ws_i, float* __restrict__ fb) {
  int* bcnt = ws_i + 16;
  int* bsrc = ws_i + 256;
  int* btrg = ws_i + 1600;
  int* bbin = ws_i + 2944;
  float* vsrc   = fb;
  float* strg   = fb + 1024;
  float* sms    = fb + 1040;
  float* escall = fb + 1048;
  float* skipb  = fb + 2648;
  float* pre1   = fb + 3160;
  float* bnf    = fb + 4096;

  __shared__ __align__(16) float s_nf2[2 * D_IN];
  __shared__ __align__(16) float s_vp[2][4][D_IN];
  __shared__ int l_cnt;
  __shared__ int l_src[SLOTS], l_trg[SLOTS], l_bin[SLOTS];

  const int bid = blockIdx.x, tid = threadIdx.x;
  const int wv = tid >> 6, ln = tid & 63;
  const int li = li_p[0], ld = ld_p[0];

  if (bid < NSCANB) {
    // ===== edge scan into private slots =====
    if (tid == 0) l_cnt = 0;
    __syncthreads();
    const int gid = bid * 512 + tid;
    const int stride = NSCANB * 512;
    const int nE4 = nE >> 2;
    const int4* t4 = (const int4*)etrg;
    for (int e4 = gid; e4 < nE4; e4 += stride) {
      int4 t = t4[e4];
      int ev[4] = {t.x, t.y, t.z, t.w};
#pragma unroll
      for (int k = 0; k < 4; ++k) {
        if (ev[k] == li || ev[k] == ld) {
          int e = e4 * 4 + k;
          int p = atomicAdd(&l_cnt, 1);
          if (p < SLOTS) { l_src[p] = esrc[e]; l_trg[p] = ev[k]; l_bin[p] = ebin[e]; }
        }
      }
    }
    if (bid == 0 && tid == 0) {          // tail (nE % 4)
      for (int e = nE4 * 4; e < nE; ++e) {
        int tv = etrg[e];
        if (tv == li || tv == ld) {
          int p = atomicAdd(&l_cnt, 1);
          if (p < SLOTS) { l_src[p] = esrc[e]; l_trg[p] = tv; l_bin[p] = ebin[e]; }
        }
      }
    }
    __syncthreads();
    int c = l_cnt; if (c > SLOTS) c = SLOTS;
    if (tid == 0) bcnt[bid] = c;         // unconditional: overwrites poison
    if (tid < c) {
      bsrc[bid * SLOTS + tid] = l_src[tid];
      btrg[bid * SLOTS + tid] = l_trg[tid];
      bbin[bid * SLOTS + tid] = l_bin[tid];
    }
    if (wv < c && ln < 32)               // dense nf-row copy (wave per match)
      ((float4*)(bnf + (size_t)(bid * SLOTS + wv) * D_IN))[ln] =
          ((const float4*)(nf + (size_t)l_src[wv] * D_IN))[ln];
    return;
  }

  if (bid < SKIP_B) {
    // ===== vsrc + strg for head h (block 219 also zeroes K2 flags) =====
    const int h = bid - VSRC_B;
    if (h == 0 && tid == 0) { ws_i[0] = 0; ws_i[1] = 0; }
    const int d = tid & 127, fg = tid >> 7;
    float as = 0.f, at = 0.f;
    for (int f = fg * 8; f < fg * 8 + 8; ++f) {
      float w = Wproj[(h * F_OUT + f) * D_IN + d];
      as = fmaf(a_src[h * F_OUT + f], w, as);
      at = fmaf(a_trg[h * F_OUT + f], w, at);
    }
    s_vp[0][fg][d] = as; s_vp[1][fg][d] = at;
    __syncthreads();
    if (tid < 128)
      vsrc[h * D_IN + tid] =
          s_vp[0][0][tid] + s_vp[0][1][tid] + s_vp[0][2][tid] + s_vp[0][3][tid];
    if (tid >= 128 && tid < 256) {
      int dd = tid - 128;
      s_vp[1][0][dd] = s_vp[1][0][dd] + s_vp[1][1][dd] + s_vp[1][2][dd] + s_vp[1][3][dd];
    }
    if (tid >= 256 && tid < 320) {
      int j = tid - 256;
      ((float4*)s_nf2)[j] = ((const float4*)(nf + (size_t)(j < 32 ? li : ld) * D_IN))[j & 31];
    }
    __syncthreads();
    if (wv < 2) {   // strg[t,h] = nf2[t] . vtrg[h]
      float part = s_nf2[wv * D_IN + ln * 2] * s_vp[1][0][ln * 2]
                 + s_nf2[wv * D_IN + ln * 2 + 1] * s_vp[1][0][ln * 2 + 1];
      part = redw(part);
      if (ln == 0) strg[wv * NH + h] = part;
    }
  } else if (bid < ESC_B) {
    // ===== skipb rows [32p, 32p+32) =====
    const int base = (bid - SKIP_B) * 32;
    if (tid < 64)
      ((float4*)s_nf2)[tid] = ((const float4*)(nf + (size_t)(tid < 32 ? li : ld) * D_IN))[tid & 31];
    __syncthreads();
    for (int rd = 0; rd < 4; ++rd) {
      int r = base + rd * 8 + wv;
      float w0 = Wskip[r * D_IN + ln * 2], w1 = Wskip[r * D_IN + ln * 2 + 1];
      float o0 = w0 * s_nf2[ln * 2] + w1 * s_nf2[ln * 2 + 1];
      float o1 = w0 * s_nf2[D_IN + ln * 2] + w1 * s_nf2[D_IN + ln * 2 + 1];
      o0 = redw(o0); o1 = redw(o1);
      if (ln == 0) { skipb[r] = o0; skipb[256 + r] = o1; }
    }
  } else if (bid < SMS_B) {
    // ===== escall bins [50p, 50p+50) =====
    const int p = bid - ESC_B;
    const int g = tid >> 3, l8 = tid & 7;
    for (int it = g; it < 50 * NH; it += 64) {
      int bin = p * 50 + (it >> 3), hh = it & 7;
      const float* de = demb_g + bin * D_EMB + l8 * 8;
      const float* wd = Wdist + hh * D_EMB + l8 * 8;
      float a = 0.f;
#pragma unroll
      for (int j = 0; j < 8; ++j) a = fmaf(de[j], wd[j], a);
#pragma unroll
      for (int o = 4; o > 0; o >>= 1) a += __shfl_down(a, o, 8);
      if (l8 == 0) escall[bin * NH + hh] = a;
    }
  } else if (bid < PRE1_B) {
    // ===== sms[h] = Wms[h] . ms (wave per head) =====
    const float* wr = Wms + wv * HID;
    float a = 0.f;
#pragma unroll
    for (int m = 0; m < 4; ++m) a = fmaf(wr[ln + 64 * m], ms[ln + 64 * m], a);
    a = redw(a);
    if (ln == 0) sms[wv] = a;
  } else {
    // ===== pre1 rows [16q, 16q+16) =====
    const int q = bid - PRE1_B;
    const int dist = dist_p[0];
    for (int rr = 0; rr < 2; ++rr) {
      int r = q * 16 + wv * 2 + rr;
      const float* w = W1 + (size_t)r * FDIM;
      float a = 0.f;
#pragma unroll
      for (int m = 0; m < 4; ++m) a = fmaf(w[ln + 64 * m], ms[ln + 64 * m], a);
      a = fmaf(w[320 + ln], demb_h[(size_t)dist * D_EMB + ln], a);
      a = redw(a);
      if (ln == 0) pre1[r] = a + b1[r];
    }
  }
}

// =====================================================================
// K2: 32 blocks; block k owns output rows [8k,8k+8) and head k>>2.
// Compacts per-block slots redundantly in LDS; dense bnf reads.
// =====================================================================
__global__ __launch_bounds__(512, 1) void finalize_k(
    const int* __restrict__ li_p,
    const float* __restrict__ Wproj, const float* __restrict__ gbias,
    const float* __restrict__ W1, const float* __restrict__ W2,
    const float* __restrict__ b2,
    int* __restrict__ ws_i, float* __restrict__ fb, float* __restrict__ out) {
  int* flag_proj = ws_i;
  int* flag_mlp  = ws_i + 1;
  int* bcnt = ws_i + 16;
  int* btrg = ws_i + 1600;
  int* bbin = ws_i + 2944;
  float* vsrc    = fb;
  float* strg    = fb + 1024;
  float* sms     = fb + 1040;
  float* escall  = fb + 1048;
  float* skipb   = fb + 2648;
  float* pre1    = fb + 3160;
  float* out_ws  = fb + 3416;
  float* partial = fb + 3928;
  float* bnf     = fb + 4096;

  __shared__ int   s_tot;
  __shared__ int   s_sl[CAP], s_tb[CAP], s_bn[CAP];
  __shared__ float s_p[CAP];
  __shared__ float s_den[2];
  __shared__ __align__(16) float s_vs[D_IN];
  __shared__ __align__(16) float s_agg[2][D_IN];
  __shared__ __align__(16) float s_out[512];
  __shared__ __align__(16) float s_emb[64];
  __shared__ float s_pr[8];

  const int k = blockIdx.x, tid = threadIdx.x;
  const int wv = tid >> 6, ln = tid & 63;
  const int li = li_p[0];
  const int h = k >> 2;
  const int row = k * 8 + wv;

  // scan-independent register preloads
  const float wpA = Wproj[row * D_IN + ln * 2];
  const float wpB = Wproj[row * D_IN + ln * 2 + 1];
  const float w1e = W1[(size_t)row * FDIM + HID + ln];
  const float w2v = W2[row];

  if (tid == 0) s_tot = 0;
  __syncthreads();
  if (tid < NSCANB) {                      // compaction of private slots
    int c = bcnt[tid];
    if (c > 0) {
      if (c > SLOTS) c = SLOTS;
      int base = atomicAdd(&s_tot, c);
      for (int j = 0; j < c; ++j)
        if (base + j < CAP) s_sl[base + j] = tid * SLOTS + j;
    }
  }
  __syncthreads();
  int cnt = s_tot; if (cnt > CAP) cnt = CAP;
  if (tid < cnt) {
    int sl = s_sl[tid];
    s_tb[tid] = (btrg[sl] == li) ? 0 : 1;
    s_bn[tid] = bbin[sl];
  }
  if (tid < D_IN) s_vs[tid] = vsrc[h * D_IN + tid];
  __syncthreads();
  const float sms_h = sms[h], strg0 = strg[h], strg1 = strg[NH + h];

  // scores: exp(leaky_relu(.)); reference's global max cancels in exp_s/denom
  for (int e = wv; e < cnt; e += 8) {
    const float* nfr = bnf + (size_t)s_sl[e] * D_IN + ln * 2;
    float part = nfr[0] * s_vs[ln * 2] + nfr[1] * s_vs[ln * 2 + 1];
    part = redw(part);
    if (ln == 0) {
      float sc = part + (s_tb[e] ? strg1 : strg0) + sms_h + escall[s_bn[e] * NH + h];
      sc = sc > 0.f ? sc : 0.2f * sc;
      s_p[e] = expf(sc);
    }
  }
  __syncthreads();
  if (tid < 2) {
    float d = 1e-16f;
    for (int e = 0; e < cnt; ++e) if (s_tb[e] == (int)tid) d += s_p[e];
    s_den[tid] = d;
  }
  __syncthreads();
  if (tid < cnt) s_p[tid] = s_p[tid] / s_den[s_tb[tid]];
  __syncthreads();
  if (tid < 256) {                         // agg[t,d] for head h (bnf L1-warm)
    const int t = tid >> 7, d = tid & 127;
    float a = 0.f;
    for (int e = 0; e < cnt; ++e)
      if (s_tb[e] == t) a = fmaf(s_p[e], bnf[(size_t)s_sl[e] * D_IN + d], a);
    s_agg[t][d] = a;
  }
  __syncthreads();
  {
    float o0 = wpA * s_agg[0][ln * 2] + wpB * s_agg[0][ln * 2 + 1];
    float o1 = wpA * s_agg[1][ln * 2] + wpB * s_agg[1][ln * 2 + 1];
    o0 = redw(o0); o1 = redw(o1);
    if (ln == 0) {
      STF(out_ws + row,       o0 + skipb[row]);
      STF(out_ws + 256 + row, o1 + skipb[256 + row]);
    }
  }
  // ---- 32-way proj barrier (relaxed flags; no fences) ----
  vm0();
  __syncthreads();
  if (tid == 0) {
    __hip_atomic_fetch_add(flag_proj, 1, AR, SA);
    while (LDF(flag_proj) < K2GRID) __builtin_amdgcn_s_sleep(1);
  }
  __syncthreads();

  // ---- MLP phase ----
  s_out[tid] = LDF(out_ws + tid);
  __syncthreads();
  if (tid < 64) {
    const int t = tid >> 5, f = tid & 31;
    float s = 0.f;
#pragma unroll
    for (int hh = 0; hh < NH; ++hh) s += s_out[t * 256 + hh * F_OUT + f];
    s = s * 0.125f + gbias[f];
    s_emb[tid] = s > 0.f ? s : expm1f(s);  // ELU
  }
  __syncthreads();
  {
    float acc = redw(w1e * s_emb[ln]);
    if (ln == 0) {
      float h1 = fmaxf(pre1[row] + acc, 0.f);
      s_pr[wv] = w2v * h1;
    }
  }
  __syncthreads();
  if (tid == 0) {
    float bp = 0.f;
#pragma unroll
    for (int w = 0; w < 8; ++w) bp += s_pr[w];
    STF(partial + k, bp);
    vm0();
    int ret = __hip_atomic_fetch_add(flag_mlp, 1, AR, SA);
    if (ret == K2GRID - 1) {               // last block finalizes
      float s = b2[0];
      for (int j = 0; j < K2GRID; ++j) s += LDF(partial + j);
      out[0] = s;
    }
  }
}

extern "C" void kernel_launch(void* const* d_in, const int* in_sizes, int n_in,
                              void* d_out, int out_size, void* d_ws, size_t ws_size,
                              hipStream_t stream) {
  const float* nf     = (const float*)d_in[0];
  const int*   esrc   = (const int*)d_in[1];
  const int*   etrg   = (const int*)d_in[2];
  const int*   ebin   = (const int*)d_in[3];
  const float* ms     = (const float*)d_in[4];
  const int*   li_p   = (const int*)d_in[5];
  const int*   ld_p   = (const int*)d_in[6];
  const int*   dist_p = (const int*)d_in[7];
  const float* Wproj  = (const float*)d_in[8];
  const float* a_src  = (const float*)d_in[9];
  const float* a_trg  = (const float*)d_in[10];
  const float* Wms    = (const float*)d_in[11];
  const float* demb_g = (const float*)d_in[12];
  const float* Wdist  = (const float*)d_in[13];
  const float* Wskip  = (const float*)d_in[14];
  const float* gbias  = (const float*)d_in[15];
  const float* demb_h = (const float*)d_in[16];
  const float* W1     = (const float*)d_in[17];
  const float* b1     = (const float*)d_in[18];
  const float* W2     = (const float*)d_in[19];
  const float* b2     = (const float*)d_in[20];
  const int nE = in_sizes[1];

  int*   ws_i = (int*)d_ws;
  float* fb   = (float*)d_ws + 8192;

  scan_pre_k<<<K1GRID, 512, 0, stream>>>(
      nf, esrc, etrg, ebin, ms, li_p, ld_p, dist_p,
      Wproj, a_src, a_trg, Wms, demb_g, Wdist, Wskip, W1, b1, demb_h,
      nE, ws_i, fb);

  finalize_k<<<K2GRID, 512, 0, stream>>>(
      li_p, Wproj, gbias, W1, W2, b2, ws_i, fb, (float*)d_out);
}